// Round 1
// baseline (1397.767 us; speedup 1.0000x reference)
//
#include <hip/hip_runtime.h>
#include <hip/hip_bf16.h>
#include <math.h>

// ---------------------------------------------------------------------------
// 2-layer TransformerConv (PyG, concat=False) + LN/ReLU + final Linear.
// N=50000 nodes, E=800000 edges, H=4 heads, C=64 ch/head, fp32 everywhere.
// ---------------------------------------------------------------------------

#define HC 256   // H*C
#define CC 64    // C

// sortable-uint encoding for float atomicMax (init = 0 == "-inf")
__device__ __forceinline__ unsigned fenc(float f) {
    unsigned u = __float_as_uint(f);
    return u ^ ((((int)u >> 31)) | 0x80000000u);
}
__device__ __forceinline__ float fdec(unsigned e) {
    unsigned u = (e >> 31) ? (e ^ 0x80000000u) : ~e;
    return __uint_as_float(u);
}

// ---------------------------------------------------------------------------
// Fused q/k/v/skip GEMM: X [n,64] -> q,k,v [n,256], acc(skip) [n,64]
// 64-node tile in LDS; thread (tn,tc) computes 4 nodes x {4 qkv cols + 1 s col}
// per ng iteration (4 iterations -> 16 nodes/thread over the 64-node tile).
// ---------------------------------------------------------------------------
__global__ __launch_bounds__(256) void qkvs_kernel(
    const float* __restrict__ X,
    const float* __restrict__ Wq, const float* __restrict__ bq,
    const float* __restrict__ Wk, const float* __restrict__ bk,
    const float* __restrict__ Wv, const float* __restrict__ bv,
    const float* __restrict__ Ws, const float* __restrict__ bs,
    float* __restrict__ q, float* __restrict__ kk, float* __restrict__ vv,
    float* __restrict__ acc, int n)
{
    __shared__ float Xs[64][64];
    const int base = blockIdx.x * 64;
    const int t = threadIdx.x;

    // stage 64x64 X tile (float4 loads, coalesced)
    for (int j = t; j < 1024; j += 256) {
        int r = j >> 4, c4 = j & 15;
        int gr = base + r;
        float4 val = make_float4(0.f, 0.f, 0.f, 0.f);
        if (gr < n) val = ((const float4*)(X + (size_t)gr * 64))[c4];
        ((float4*)Xs[r])[c4] = val;
    }
    __syncthreads();

    const int tc = t & 63;
    const int tn = t >> 6;

    for (int ng = 0; ng < 4; ++ng) {
        float aq[4][4] = {}, ak[4][4] = {}, av[4][4] = {}, as[4] = {};
        #pragma unroll 4
        for (int k0 = 0; k0 < 64; ++k0) {
            float xr[4];
            #pragma unroll
            for (int j = 0; j < 4; ++j)
                xr[j] = Xs[tn + 4 * ng + 16 * j][k0];
            #pragma unroll
            for (int cb = 0; cb < 4; ++cb) {
                float wq = Wq[k0 * HC + cb * 64 + tc];
                float wk = Wk[k0 * HC + cb * 64 + tc];
                float wv = Wv[k0 * HC + cb * 64 + tc];
                #pragma unroll
                for (int j = 0; j < 4; ++j) {
                    aq[j][cb] = fmaf(xr[j], wq, aq[j][cb]);
                    ak[j][cb] = fmaf(xr[j], wk, ak[j][cb]);
                    av[j][cb] = fmaf(xr[j], wv, av[j][cb]);
                }
            }
            float ws_ = Ws[k0 * CC + tc];
            #pragma unroll
            for (int j = 0; j < 4; ++j) as[j] = fmaf(xr[j], ws_, as[j]);
        }
        #pragma unroll
        for (int j = 0; j < 4; ++j) {
            int gr = base + tn + 4 * ng + 16 * j;
            if (gr >= n) continue;
            size_t ro = (size_t)gr * HC;
            #pragma unroll
            for (int cb = 0; cb < 4; ++cb) {
                q[ro + cb * 64 + tc]  = aq[j][cb] + bq[cb * 64 + tc];
                kk[ro + cb * 64 + tc] = ak[j][cb] + bk[cb * 64 + tc];
                vv[ro + cb * 64 + tc] = av[j][cb] + bv[cb * 64 + tc];
            }
            acc[(size_t)gr * CC + tc] = as[j] + bs[tc];
        }
    }
}

// ---------------------------------------------------------------------------
// Pass 1: per-edge logits alpha[e][h] = dot(q[dst,h], k[src,h]) / 8
//         + segment max via atomicMax (sortable uint). Wave per edge.
// ---------------------------------------------------------------------------
__global__ __launch_bounds__(256) void edge_alpha_kernel(
    const int* __restrict__ src, const int* __restrict__ dst,
    const float* __restrict__ q, const float* __restrict__ kk,
    float* __restrict__ alpha, unsigned* __restrict__ amax, int E)
{
    int e = (int)((blockIdx.x * 256 + threadIdx.x) >> 6);
    int lane = threadIdx.x & 63;
    if (e >= E) return;
    int s = src[e], d = dst[e];
    const float* qr = q + (size_t)d * HC;
    const float* kr = kk + (size_t)s * HC;
    float p0 = qr[lane]       * kr[lane];
    float p1 = qr[64 + lane]  * kr[64 + lane];
    float p2 = qr[128 + lane] * kr[128 + lane];
    float p3 = qr[192 + lane] * kr[192 + lane];
    #pragma unroll
    for (int off = 32; off; off >>= 1) {
        p0 += __shfl_xor(p0, off);
        p1 += __shfl_xor(p1, off);
        p2 += __shfl_xor(p2, off);
        p3 += __shfl_xor(p3, off);
    }
    if (lane < 4) {
        float a = (lane == 0) ? p0 : (lane == 1) ? p1 : (lane == 2) ? p2 : p3;
        a *= 0.125f;  // 1/sqrt(C)
        alpha[(size_t)e * 4 + lane] = a;
        atomicMax(&amax[(size_t)d * 4 + lane], fenc(a));
    }
}

// ---------------------------------------------------------------------------
// Pass 2: ex = exp(alpha - amax[dst]); store in-place; denom += ex.
// Thread per (edge, head).
// ---------------------------------------------------------------------------
__global__ __launch_bounds__(256) void edge_exp_kernel(
    const int* __restrict__ dst, float* __restrict__ alpha,
    const unsigned* __restrict__ amax, float* __restrict__ denom, int E)
{
    int idx = blockIdx.x * 256 + threadIdx.x;
    if (idx >= E * 4) return;
    int e = idx >> 2, h = idx & 3;
    int d = dst[e];
    float m = fdec(amax[(size_t)d * 4 + h]);
    float ex = __expf(alpha[idx] - m);
    alpha[idx] = ex;
    atomicAdd(&denom[(size_t)d * 4 + h], ex);
}

// ---------------------------------------------------------------------------
// Pass 3: msg[c] = sum_h attn[h] * v[src][h*64+c] / H; atomicAdd into acc.
// Wave per edge (64 atomics/edge, head-mean folded in).
// ---------------------------------------------------------------------------
__global__ __launch_bounds__(256) void edge_scatter_kernel(
    const int* __restrict__ src, const int* __restrict__ dst,
    const float* __restrict__ ex, const float* __restrict__ denom,
    const float* __restrict__ vv, float* __restrict__ acc, int E)
{
    int e = (int)((blockIdx.x * 256 + threadIdx.x) >> 6);
    int lane = threadIdx.x & 63;
    if (e >= E) return;
    int s = src[e], d = dst[e];
    float at0 = ex[(size_t)e * 4 + 0] / (denom[(size_t)d * 4 + 0] + 1e-16f) * 0.25f;
    float at1 = ex[(size_t)e * 4 + 1] / (denom[(size_t)d * 4 + 1] + 1e-16f) * 0.25f;
    float at2 = ex[(size_t)e * 4 + 2] / (denom[(size_t)d * 4 + 2] + 1e-16f) * 0.25f;
    float at3 = ex[(size_t)e * 4 + 3] / (denom[(size_t)d * 4 + 3] + 1e-16f) * 0.25f;
    const float* vr = vv + (size_t)s * HC;
    float m = at0 * vr[lane] + at1 * vr[64 + lane] + at2 * vr[128 + lane] + at3 * vr[192 + lane];
    atomicAdd(&acc[(size_t)d * CC + lane], m);
}

// ---------------------------------------------------------------------------
// LayerNorm (+optional ReLU), wave per node, lane = channel.
// ---------------------------------------------------------------------------
template <bool RELU>
__global__ __launch_bounds__(256) void ln_kernel(
    const float* __restrict__ acc, const float* __restrict__ g,
    const float* __restrict__ b, float* __restrict__ out, int n)
{
    int node = blockIdx.x * 4 + (threadIdx.x >> 6);
    int lane = threadIdx.x & 63;
    if (node >= n) return;
    float val = acc[(size_t)node * CC + lane];
    float s = val;
    #pragma unroll
    for (int off = 32; off; off >>= 1) s += __shfl_xor(s, off);
    float mu = s * (1.f / 64.f);
    float dv = val - mu;
    float vs = dv * dv;
    #pragma unroll
    for (int off = 32; off; off >>= 1) vs += __shfl_xor(vs, off);
    float var = vs * (1.f / 64.f);
    float y = dv * rsqrtf(var + 1e-5f) * g[lane] + b[lane];
    if (RELU) y = fmaxf(y, 0.f);
    out[(size_t)node * CC + lane] = y;
}

// ---------------------------------------------------------------------------
// Final: LayerNorm (no relu) then Linear 64->32 into d_out. 4 nodes/block.
// ---------------------------------------------------------------------------
__global__ __launch_bounds__(256) void ln_final_kernel(
    const float* __restrict__ acc, const float* __restrict__ g,
    const float* __restrict__ b, const float* __restrict__ Wf,
    const float* __restrict__ bf, float* __restrict__ out, int n)
{
    __shared__ float ys[4][64];
    int nb = blockIdx.x * 4;
    int node = nb + (threadIdx.x >> 6);
    int lane = threadIdx.x & 63;
    if (node < n) {
        float val = acc[(size_t)node * CC + lane];
        float s = val;
        #pragma unroll
        for (int off = 32; off; off >>= 1) s += __shfl_xor(s, off);
        float mu = s * (1.f / 64.f);
        float dv = val - mu;
        float vs = dv * dv;
        #pragma unroll
        for (int off = 32; off; off >>= 1) vs += __shfl_xor(vs, off);
        float var = vs * (1.f / 64.f);
        ys[threadIdx.x >> 6][lane] = dv * rsqrtf(var + 1e-5f) * g[lane] + b[lane];
    }
    __syncthreads();
    int t = threadIdx.x;
    if (t < 128) {
        int j = t >> 5, o = t & 31;
        int gn = nb + j;
        if (gn < n) {
            float a = bf[o];
            #pragma unroll
            for (int c = 0; c < 64; ++c) a = fmaf(ys[j][c], Wf[c * 32 + o], a);
            out[(size_t)gn * 32 + o] = a;
        }
    }
}

// ---------------------------------------------------------------------------
extern "C" void kernel_launch(void* const* d_in, const int* in_sizes, int n_in,
                              void* d_out, int out_size, void* d_ws, size_t ws_size,
                              hipStream_t stream)
{
    const float* x   = (const float*)d_in[0];
    const int*   ei  = (const int*)d_in[1];
    const float* Wq1 = (const float*)d_in[2];  const float* bq1 = (const float*)d_in[3];
    const float* Wk1 = (const float*)d_in[4];  const float* bk1 = (const float*)d_in[5];
    const float* Wv1 = (const float*)d_in[6];  const float* bv1 = (const float*)d_in[7];
    const float* Ws1 = (const float*)d_in[8];  const float* bs1 = (const float*)d_in[9];
    const float* Wq2 = (const float*)d_in[10]; const float* bq2 = (const float*)d_in[11];
    const float* Wk2 = (const float*)d_in[12]; const float* bk2 = (const float*)d_in[13];
    const float* Wv2 = (const float*)d_in[14]; const float* bv2 = (const float*)d_in[15];
    const float* Ws2 = (const float*)d_in[16]; const float* bs2 = (const float*)d_in[17];
    const float* lng = (const float*)d_in[18]; const float* lnb = (const float*)d_in[19];
    const float* Wf  = (const float*)d_in[20]; const float* bf  = (const float*)d_in[21];

    const int N = in_sizes[0] / 64;
    const int E = in_sizes[1] / 2;
    const int* src  = ei;
    const int* dstp = ei + E;

    float* ws = (float*)d_ws;
    float*    q     = ws;                          // N*256
    float*    kk    = q + (size_t)N * HC;          // N*256
    float*    vv    = kk + (size_t)N * HC;         // N*256
    float*    ex    = vv + (size_t)N * HC;         // E*4
    unsigned* amax  = (unsigned*)(ex + (size_t)E * 4);  // N*4
    float*    denom = (float*)(amax + (size_t)N * 4);   // N*4
    float*    acc   = denom + (size_t)N * 4;       // N*64
    float*    hbuf  = acc + (size_t)N * CC;        // N*64

    const int gemm_blocks = (N + 63) / 64;
    const int edge_blocks = (E + 3) / 4;      // wave per edge, 4 waves/block
    const int exp_blocks  = (E * 4 + 255) / 256;
    const int ln_blocks   = (N + 3) / 4;

    // ---- conv1 ----
    qkvs_kernel<<<gemm_blocks, 256, 0, stream>>>(x, Wq1, bq1, Wk1, bk1, Wv1, bv1,
                                                 Ws1, bs1, q, kk, vv, acc, N);
    hipMemsetAsync(amax, 0, (size_t)N * 8 * sizeof(unsigned), stream);
    edge_alpha_kernel<<<edge_blocks, 256, 0, stream>>>(src, dstp, q, kk, ex, amax, E);
    edge_exp_kernel<<<exp_blocks, 256, 0, stream>>>(dstp, ex, amax, denom, E);
    edge_scatter_kernel<<<edge_blocks, 256, 0, stream>>>(src, dstp, ex, denom, vv, acc, E);
    ln_kernel<true><<<ln_blocks, 256, 0, stream>>>(acc, lng, lnb, hbuf, N);

    // ---- conv2 ----
    qkvs_kernel<<<gemm_blocks, 256, 0, stream>>>(hbuf, Wq2, bq2, Wk2, bk2, Wv2, bv2,
                                                 Ws2, bs2, q, kk, vv, acc, N);
    hipMemsetAsync(amax, 0, (size_t)N * 8 * sizeof(unsigned), stream);
    edge_alpha_kernel<<<edge_blocks, 256, 0, stream>>>(src, dstp, q, kk, ex, amax, E);
    edge_exp_kernel<<<exp_blocks, 256, 0, stream>>>(dstp, ex, amax, denom, E);
    edge_scatter_kernel<<<edge_blocks, 256, 0, stream>>>(src, dstp, ex, denom, vv, acc, E);

    // ---- final LN + linear ----
    ln_final_kernel<<<ln_blocks, 256, 0, stream>>>(acc, lng, lnb, Wf, bf,
                                                   (float*)d_out, N);
}

// Round 2
// 771.260 us; speedup vs baseline: 1.8123x; 1.8123x over previous
//
#include <hip/hip_runtime.h>
#include <hip/hip_bf16.h>
#include <math.h>

typedef unsigned short u16;
typedef __attribute__((ext_vector_type(8))) short bf16x8;
typedef __attribute__((ext_vector_type(4))) float f32x4;

__device__ __forceinline__ u16 f2bf(float f) {
    unsigned u = __float_as_uint(f);
    u += 0x7fffu + ((u >> 16) & 1u);   // RNE
    return (u16)(u >> 16);
}
__device__ __forceinline__ float bf2f(u16 h) {
    return __uint_as_float(((unsigned)h) << 16);
}

// ---------------------------------------------------------------------------
// fp32 -> bf16 conversion of X (N*64 elems), float4 -> ushort4
// ---------------------------------------------------------------------------
__global__ __launch_bounds__(256) void convert_x(
    const float* __restrict__ x, u16* __restrict__ xbf, int total4)
{
    int i = blockIdx.x * 256 + threadIdx.x;
    if (i >= total4) return;
    float4 v = ((const float4*)x)[i];
    ushort4 o;
    o.x = f2bf(v.x); o.y = f2bf(v.y); o.z = f2bf(v.z); o.w = f2bf(v.w);
    ((ushort4*)xbf)[i] = o;
}

// ---------------------------------------------------------------------------
// Build transposed bf16 weight block wt[832][64] (cols: 0-255 q, 256-511 k,
// 512-767 v, 768-831 s) + concatenated fp32 bias ba[832].
// ---------------------------------------------------------------------------
__global__ __launch_bounds__(256) void convert_w(
    const float* __restrict__ Wq, const float* __restrict__ Wk,
    const float* __restrict__ Wv, const float* __restrict__ Ws,
    const float* __restrict__ bq, const float* __restrict__ bk,
    const float* __restrict__ bv, const float* __restrict__ bs,
    u16* __restrict__ wt, float* __restrict__ ba)
{
    int idx = blockIdx.x * 256 + threadIdx.x;
    if (idx >= 832 * 64) return;
    int col = idx >> 6, k = idx & 63;
    float w;
    if      (col < 256) w = Wq[k * 256 + col];
    else if (col < 512) w = Wk[k * 256 + (col - 256)];
    else if (col < 768) w = Wv[k * 256 + (col - 512)];
    else                w = Ws[k * 64  + (col - 768)];
    wt[col * 64 + k] = f2bf(w);
    if (k == 0)
        ba[col] = (col < 256) ? bq[col] : (col < 512) ? bk[col - 256]
                 : (col < 768) ? bv[col - 512] : bs[col - 768];
}

// ---------------------------------------------------------------------------
// CSR build: histogram, single-block scan, fill
// ---------------------------------------------------------------------------
__global__ __launch_bounds__(256) void hist_kernel(
    const int* __restrict__ dst, int* __restrict__ deg, int E)
{
    int e = blockIdx.x * 256 + threadIdx.x;
    if (e < E) atomicAdd(&deg[dst[e]], 1);
}

__global__ __launch_bounds__(1024) void scan_kernel(
    const int* __restrict__ deg, int* __restrict__ off,
    int* __restrict__ cursor, int n)
{
    __shared__ int ps[1024];
    int t = threadIdx.x;
    int chunk = (n + 1023) / 1024;
    int lo = t * chunk, hi = min(lo + chunk, n);
    int s = 0;
    for (int i = lo; i < hi; ++i) s += deg[i];
    ps[t] = s;
    __syncthreads();
    for (int d = 1; d < 1024; d <<= 1) {
        int v = (t >= d) ? ps[t - d] : 0;
        __syncthreads();
        ps[t] += v;
        __syncthreads();
    }
    int run = t ? ps[t - 1] : 0;
    for (int i = lo; i < hi; ++i) {
        off[i] = run; cursor[i] = run; run += deg[i];
    }
    if (t == 0) off[n] = ps[1023];
}

__global__ __launch_bounds__(256) void fill_kernel(
    const int* __restrict__ src, const int* __restrict__ dst,
    int* __restrict__ cursor, int* __restrict__ csr_src, int E)
{
    int e = blockIdx.x * 256 + threadIdx.x;
    if (e >= E) return;
    int slot = atomicAdd(&cursor[dst[e]], 1);
    csr_src[slot] = src[e];
}

// ---------------------------------------------------------------------------
// bf16 MFMA GEMM: xbf [n,64] @ wt^T -> qb,kb,vb bf16 [n,256], skip fp32 [n,64]
// block = 256 thr = 4 waves; wave w covers cols [w*208, w*208+208); 16 nodes.
// A,B use the SAME (lane,reg)->k mapping -> dot is layout-permutation-safe.
// C/D: col = lane&15, row = (lane>>4)*4 + reg  [HW-verified]
// ---------------------------------------------------------------------------
__global__ __launch_bounds__(256) void gemm_qkvs(
    const u16* __restrict__ xbf, const u16* __restrict__ wt,
    const float* __restrict__ ba,
    u16* __restrict__ qb, u16* __restrict__ kb, u16* __restrict__ vb,
    float* __restrict__ skip, int n)
{
    const int w = threadIdx.x >> 6, lane = threadIdx.x & 63;
    const int r = lane & 15, g = lane >> 4;
    const int node0 = blockIdx.x * 16;

    int nr = node0 + r; if (nr >= n) nr = n - 1;
    const u16* xr = xbf + (size_t)nr * 64 + g * 8;
    bf16x8 a0 = *(const bf16x8*)xr;
    bf16x8 a1 = *(const bf16x8*)(xr + 32);

    const int colbase = w * 208;
    for (int ct = 0; ct < 13; ++ct) {
        int col = colbase + ct * 16 + r;
        const u16* wr = wt + (size_t)col * 64 + g * 8;
        bf16x8 b0 = *(const bf16x8*)wr;
        bf16x8 b1 = *(const bf16x8*)(wr + 32);
        f32x4 acc = {0.f, 0.f, 0.f, 0.f};
        acc = __builtin_amdgcn_mfma_f32_16x16x32_bf16(a0, b0, acc, 0, 0, 0);
        acc = __builtin_amdgcn_mfma_f32_16x16x32_bf16(a1, b1, acc, 0, 0, 0);
        float bias = ba[col];
        #pragma unroll
        for (int reg = 0; reg < 4; ++reg) {
            int node = node0 + g * 4 + reg;
            if (node >= n) continue;
            float v = acc[reg] + bias;
            if (col < 768) {
                int which = col >> 8, c = col & 255;
                u16* dp = (which == 0) ? qb : (which == 1) ? kb : vb;
                dp[(size_t)node * 256 + c] = f2bf(v);
            } else {
                skip[(size_t)node * 64 + (col - 768)] = v;
            }
        }
    }
}

// ---------------------------------------------------------------------------
// Fused attention: wave per dst node, online softmax over CSR in-edges,
// head-mean + skip + LayerNorm (+ReLU) epilogue. lane = channel.
// ---------------------------------------------------------------------------
template <int RELU, int BF16OUT>
__global__ __launch_bounds__(256) void fused_attn(
    const u16* __restrict__ qb, const u16* __restrict__ kb,
    const u16* __restrict__ vb, const float* __restrict__ skip,
    const int* __restrict__ off, const int* __restrict__ csr_src,
    const float* __restrict__ lng, const float* __restrict__ lnb,
    u16* __restrict__ out_bf, float* __restrict__ out_f, int n)
{
    int node = blockIdx.x * 4 + (threadIdx.x >> 6);
    int lane = threadIdx.x & 63;
    if (node >= n) return;

    const u16* qr = qb + (size_t)node * 256;
    float q0 = bf2f(qr[lane]),       q1 = bf2f(qr[64 + lane]);
    float q2 = bf2f(qr[128 + lane]), q3 = bf2f(qr[192 + lane]);

    float m0 = -1e30f, m1 = -1e30f, m2 = -1e30f, m3 = -1e30f;
    float l0 = 0.f, l1 = 0.f, l2 = 0.f, l3 = 0.f;
    float a0 = 0.f, a1 = 0.f, a2 = 0.f, a3 = 0.f;

    int s0 = off[node], s1 = off[node + 1];
    for (int i = s0; i < s1; ++i) {
        int s = csr_src[i];
        const u16* kr = kb + (size_t)s * 256;
        float p0 = q0 * bf2f(kr[lane]);
        float p1 = q1 * bf2f(kr[64 + lane]);
        float p2 = q2 * bf2f(kr[128 + lane]);
        float p3 = q3 * bf2f(kr[192 + lane]);
        #pragma unroll
        for (int o = 32; o; o >>= 1) {
            p0 += __shfl_xor(p0, o);
            p1 += __shfl_xor(p1, o);
            p2 += __shfl_xor(p2, o);
            p3 += __shfl_xor(p3, o);
        }
        p0 *= 0.125f; p1 *= 0.125f; p2 *= 0.125f; p3 *= 0.125f;

        float n0 = fmaxf(m0, p0), n1 = fmaxf(m1, p1);
        float n2 = fmaxf(m2, p2), n3 = fmaxf(m3, p3);
        float c0 = __expf(m0 - n0), c1 = __expf(m1 - n1);
        float c2 = __expf(m2 - n2), c3 = __expf(m3 - n3);
        float e0 = __expf(p0 - n0), e1 = __expf(p1 - n1);
        float e2 = __expf(p2 - n2), e3 = __expf(p3 - n3);
        m0 = n0; m1 = n1; m2 = n2; m3 = n3;
        l0 = l0 * c0 + e0; l1 = l1 * c1 + e1;
        l2 = l2 * c2 + e2; l3 = l3 * c3 + e3;

        const u16* vr = vb + (size_t)s * 256;
        a0 = a0 * c0 + e0 * bf2f(vr[lane]);
        a1 = a1 * c1 + e1 * bf2f(vr[64 + lane]);
        a2 = a2 * c2 + e2 * bf2f(vr[128 + lane]);
        a3 = a3 * c3 + e3 * bf2f(vr[192 + lane]);
    }

    float outv = 0.25f * (a0 / (l0 + 1e-16f) + a1 / (l1 + 1e-16f) +
                          a2 / (l2 + 1e-16f) + a3 / (l3 + 1e-16f));
    outv += skip[(size_t)node * 64 + lane];

    // LayerNorm across the wave (64 channels)
    float s = outv;
    #pragma unroll
    for (int o = 32; o; o >>= 1) s += __shfl_xor(s, o);
    float mu = s * (1.f / 64.f);
    float dv = outv - mu;
    float vs = dv * dv;
    #pragma unroll
    for (int o = 32; o; o >>= 1) vs += __shfl_xor(vs, o);
    float y = dv * rsqrtf(vs * (1.f / 64.f) + 1e-5f) * lng[lane] + lnb[lane];
    if (RELU) y = fmaxf(y, 0.f);

    if (BF16OUT) out_bf[(size_t)node * 64 + lane] = f2bf(y);
    else         out_f [(size_t)node * 64 + lane] = y;
}

// ---------------------------------------------------------------------------
// Final Linear 64->32 (LN already applied by fused_attn<0,0>)
// ---------------------------------------------------------------------------
__global__ __launch_bounds__(256) void final_matvec(
    const float* __restrict__ y, const float* __restrict__ Wf,
    const float* __restrict__ bfv, float* __restrict__ out, int n)
{
    __shared__ float ys[8][64];
    int nb = blockIdx.x * 8;
    for (int i = threadIdx.x; i < 512; i += 256) {
        int r = i >> 6, c = i & 63;
        int gn = nb + r;
        ys[r][c] = (gn < n) ? y[(size_t)gn * 64 + c] : 0.f;
    }
    __syncthreads();
    int r = threadIdx.x >> 5, o = threadIdx.x & 31;
    int gn = nb + r;
    if (gn < n) {
        float a = bfv[o];
        #pragma unroll
        for (int c = 0; c < 64; ++c) a = fmaf(ys[r][c], Wf[c * 32 + o], a);
        out[(size_t)gn * 32 + o] = a;
    }
}

// ---------------------------------------------------------------------------
extern "C" void kernel_launch(void* const* d_in, const int* in_sizes, int n_in,
                              void* d_out, int out_size, void* d_ws, size_t ws_size,
                              hipStream_t stream)
{
    const float* x   = (const float*)d_in[0];
    const int*   ei  = (const int*)d_in[1];
    const float* Wq1 = (const float*)d_in[2];  const float* bq1 = (const float*)d_in[3];
    const float* Wk1 = (const float*)d_in[4];  const float* bk1 = (const float*)d_in[5];
    const float* Wv1 = (const float*)d_in[6];  const float* bv1 = (const float*)d_in[7];
    const float* Ws1 = (const float*)d_in[8];  const float* bs1 = (const float*)d_in[9];
    const float* Wq2 = (const float*)d_in[10]; const float* bq2 = (const float*)d_in[11];
    const float* Wk2 = (const float*)d_in[12]; const float* bk2 = (const float*)d_in[13];
    const float* Wv2 = (const float*)d_in[14]; const float* bv2 = (const float*)d_in[15];
    const float* Ws2 = (const float*)d_in[16]; const float* bs2 = (const float*)d_in[17];
    const float* lng = (const float*)d_in[18]; const float* lnb = (const float*)d_in[19];
    const float* Wf  = (const float*)d_in[20]; const float* bf  = (const float*)d_in[21];

    const int N = in_sizes[0] / 64;
    const int E = in_sizes[1] / 2;
    const int* src  = ei;
    const int* dstp = ei + E;

    char* p = (char*)d_ws;
    u16* qb   = (u16*)p; p += (size_t)N * 256 * 2;
    u16* kb   = (u16*)p; p += (size_t)N * 256 * 2;
    u16* vb   = (u16*)p; p += (size_t)N * 256 * 2;
    u16* xbf  = (u16*)p; p += (size_t)N * 64 * 2;   // conv1 in; conv1 out (h, bf16)
    u16* wt1  = (u16*)p; p += 832 * 64 * 2;
    u16* wt2  = (u16*)p; p += 832 * 64 * 2;
    float* ba1  = (float*)p; p += 832 * 4;
    float* ba2  = (float*)p; p += 832 * 4;
    float* skip = (float*)p; p += (size_t)N * 64 * 4;
    float* y2   = (float*)p; p += (size_t)N * 64 * 4;
    int* deg    = (int*)p; p += (size_t)N * 4;
    int* off    = (int*)p; p += ((size_t)N + 1) * 4;
    int* cursor = (int*)p; p += (size_t)N * 4;
    int* csr    = (int*)p; p += (size_t)E * 4;

    const int cvx_blocks  = (N * 16 + 255) / 256;     // N*64/4 elems
    const int cvw_blocks  = (832 * 64 + 255) / 256;
    const int e_blocks    = (E + 255) / 256;
    const int gemm_blocks = (N + 15) / 16;
    const int attn_blocks = (N + 3) / 4;
    const int fin_blocks  = (N + 7) / 8;

    // ---- prep: conversions + CSR ----
    convert_x<<<cvx_blocks, 256, 0, stream>>>(x, xbf, N * 16);
    convert_w<<<cvw_blocks, 256, 0, stream>>>(Wq1, Wk1, Wv1, Ws1, bq1, bk1, bv1, bs1, wt1, ba1);
    convert_w<<<cvw_blocks, 256, 0, stream>>>(Wq2, Wk2, Wv2, Ws2, bq2, bk2, bv2, bs2, wt2, ba2);
    hipMemsetAsync(deg, 0, (size_t)N * 4, stream);
    hist_kernel<<<e_blocks, 256, 0, stream>>>(dstp, deg, E);
    scan_kernel<<<1, 1024, 0, stream>>>(deg, off, cursor, N);
    fill_kernel<<<e_blocks, 256, 0, stream>>>(src, dstp, cursor, csr, E);

    // ---- conv1 ----
    gemm_qkvs<<<gemm_blocks, 256, 0, stream>>>(xbf, wt1, ba1, qb, kb, vb, skip, N);
    fused_attn<1, 1><<<attn_blocks, 256, 0, stream>>>(qb, kb, vb, skip, off, csr,
                                                      lng, lnb, xbf, nullptr, N);
    // ---- conv2 ----
    gemm_qkvs<<<gemm_blocks, 256, 0, stream>>>(xbf, wt2, ba2, qb, kb, vb, skip, N);
    fused_attn<0, 0><<<attn_blocks, 256, 0, stream>>>(qb, kb, vb, skip, off, csr,
                                                      lng, lnb, nullptr, y2, N);
    // ---- final linear ----
    final_matvec<<<fin_blocks, 256, 0, stream>>>(y2, Wf, bf, (float*)d_out, N);
}

// Round 3
// 601.186 us; speedup vs baseline: 2.3250x; 1.2829x over previous
//
#include <hip/hip_runtime.h>
#include <hip/hip_bf16.h>
#include <math.h>

typedef unsigned short u16;
typedef __attribute__((ext_vector_type(8))) short bf16x8;
typedef __attribute__((ext_vector_type(4))) float f32x4;

__device__ __forceinline__ u16 f2bf(float f) {
    unsigned u = __float_as_uint(f);
    u += 0x7fffu + ((u >> 16) & 1u);   // RNE
    return (u16)(u >> 16);
}
__device__ __forceinline__ float bf2f(u16 h) {
    return __uint_as_float(((unsigned)h) << 16);
}

// ---------------------------------------------------------------------------
// fp32 -> bf16 conversion of X (N*64 elems), float4 -> ushort4
// ---------------------------------------------------------------------------
__global__ __launch_bounds__(256) void convert_x(
    const float* __restrict__ x, u16* __restrict__ xbf, int total4)
{
    int i = blockIdx.x * 256 + threadIdx.x;
    if (i >= total4) return;
    float4 v = ((const float4*)x)[i];
    ushort4 o;
    o.x = f2bf(v.x); o.y = f2bf(v.y); o.z = f2bf(v.z); o.w = f2bf(v.w);
    ((ushort4*)xbf)[i] = o;
}

// ---------------------------------------------------------------------------
// Build transposed bf16 weight block wt[832][64] (cols: 0-255 q, 256-511 k,
// 512-767 v, 768-831 s) + concatenated fp32 bias ba[832].
// ---------------------------------------------------------------------------
__global__ __launch_bounds__(256) void convert_w(
    const float* __restrict__ Wq, const float* __restrict__ Wk,
    const float* __restrict__ Wv, const float* __restrict__ Ws,
    const float* __restrict__ bq, const float* __restrict__ bk,
    const float* __restrict__ bv, const float* __restrict__ bs,
    u16* __restrict__ wt, float* __restrict__ ba)
{
    int idx = blockIdx.x * 256 + threadIdx.x;
    if (idx >= 832 * 64) return;
    int col = idx >> 6, k = idx & 63;
    float w;
    if      (col < 256) w = Wq[k * 256 + col];
    else if (col < 512) w = Wk[k * 256 + (col - 256)];
    else if (col < 768) w = Wv[k * 256 + (col - 512)];
    else                w = Ws[k * 64  + (col - 768)];
    wt[col * 64 + k] = f2bf(w);
    if (k == 0)
        ba[col] = (col < 256) ? bq[col] : (col < 512) ? bk[col - 256]
                 : (col < 768) ? bv[col - 512] : bs[col - 768];
}

// ---------------------------------------------------------------------------
// CSR build: histogram, single-block scan, fill
// ---------------------------------------------------------------------------
__global__ __launch_bounds__(256) void hist_kernel(
    const int* __restrict__ dst, int* __restrict__ deg, int E)
{
    int e = blockIdx.x * 256 + threadIdx.x;
    if (e < E) atomicAdd(&deg[dst[e]], 1);
}

__global__ __launch_bounds__(1024) void scan_kernel(
    const int* __restrict__ deg, int* __restrict__ off,
    int* __restrict__ cursor, int n)
{
    __shared__ int ps[1024];
    int t = threadIdx.x;
    int chunk = (n + 1023) / 1024;
    int lo = t * chunk, hi = min(lo + chunk, n);
    int s = 0;
    for (int i = lo; i < hi; ++i) s += deg[i];
    ps[t] = s;
    __syncthreads();
    for (int d = 1; d < 1024; d <<= 1) {
        int v = (t >= d) ? ps[t - d] : 0;
        __syncthreads();
        ps[t] += v;
        __syncthreads();
    }
    int run = t ? ps[t - 1] : 0;
    for (int i = lo; i < hi; ++i) {
        off[i] = run; cursor[i] = run; run += deg[i];
    }
    if (t == 0) off[n] = ps[1023];
}

__global__ __launch_bounds__(256) void fill_kernel(
    const int* __restrict__ src, const int* __restrict__ dst,
    int* __restrict__ cursor, int* __restrict__ csr_src, int E)
{
    int e = blockIdx.x * 256 + threadIdx.x;
    if (e >= E) return;
    int slot = atomicAdd(&cursor[dst[e]], 1);
    csr_src[slot] = src[e];
}

// ---------------------------------------------------------------------------
// bf16 MFMA GEMM: xbf [n,64] @ wt^T -> qb,kb,vb bf16 [n,256], skip fp32 [n,64]
// block = 256 thr = 4 waves; wave w covers cols [w*208, w*208+208); 16 nodes.
// A,B use the SAME (lane,reg)->k mapping -> dot is layout-permutation-safe.
// C/D: col = lane&15, row = (lane>>4)*4 + reg  [HW-verified]
// ---------------------------------------------------------------------------
__global__ __launch_bounds__(256) void gemm_qkvs(
    const u16* __restrict__ xbf, const u16* __restrict__ wt,
    const float* __restrict__ ba,
    u16* __restrict__ qb, u16* __restrict__ kb, u16* __restrict__ vb,
    float* __restrict__ skip, int n)
{
    const int w = threadIdx.x >> 6, lane = threadIdx.x & 63;
    const int r = lane & 15, g = lane >> 4;
    const int node0 = blockIdx.x * 16;

    int nr = node0 + r; if (nr >= n) nr = n - 1;
    const u16* xr = xbf + (size_t)nr * 64 + g * 8;
    bf16x8 a0 = *(const bf16x8*)xr;
    bf16x8 a1 = *(const bf16x8*)(xr + 32);

    const int colbase = w * 208;
    for (int ct = 0; ct < 13; ++ct) {
        int col = colbase + ct * 16 + r;
        const u16* wr = wt + (size_t)col * 64 + g * 8;
        bf16x8 b0 = *(const bf16x8*)wr;
        bf16x8 b1 = *(const bf16x8*)(wr + 32);
        f32x4 acc = {0.f, 0.f, 0.f, 0.f};
        acc = __builtin_amdgcn_mfma_f32_16x16x32_bf16(a0, b0, acc, 0, 0, 0);
        acc = __builtin_amdgcn_mfma_f32_16x16x32_bf16(a1, b1, acc, 0, 0, 0);
        float bias = ba[col];
        #pragma unroll
        for (int reg = 0; reg < 4; ++reg) {
            int node = node0 + g * 4 + reg;
            if (node >= n) continue;
            float v = acc[reg] + bias;
            if (col < 768) {
                int which = col >> 8, c = col & 255;
                u16* dp = (which == 0) ? qb : (which == 1) ? kb : vb;
                dp[(size_t)node * 256 + c] = f2bf(v);
            } else {
                skip[(size_t)node * 64 + (col - 768)] = v;
            }
        }
    }
}

// ---------------------------------------------------------------------------
// Fused attention: wave per dst node, online softmax over CSR in-edges.
// Lane layout: lane = h*16 + c4; lane holds channels h*64 + c4*4 .. +3,
// i.e. row byte-offset = lane*8 -> one coalesced ushort4 per lane covers
// the full 256-ch row. Per-head dot reduce = 4-level butterfly over 16
// lanes (all heads in parallel) -> 4 DS ops/edge instead of 24.
// Epilogue: head-mean (2 shfl) + skip + LayerNorm (+ReLU) fused.
// ---------------------------------------------------------------------------
template <int RELU, int BF16OUT>
__global__ __launch_bounds__(256) void fused_attn(
    const u16* __restrict__ qb, const u16* __restrict__ kb,
    const u16* __restrict__ vb, const float* __restrict__ skip,
    const int* __restrict__ off, const int* __restrict__ csr_src,
    const float* __restrict__ lng, const float* __restrict__ lnb,
    u16* __restrict__ out_bf, float* __restrict__ out_f, int n)
{
    int node = blockIdx.x * 4 + (threadIdx.x >> 6);
    int lane = threadIdx.x & 63;
    if (node >= n) return;
    const int c4 = lane & 15;

    ushort4 qw = ((const ushort4*)(qb + (size_t)node * 256))[lane];
    const float q0 = bf2f(qw.x) * 0.125f, q1 = bf2f(qw.y) * 0.125f;
    const float q2 = bf2f(qw.z) * 0.125f, q3 = bf2f(qw.w) * 0.125f;

    float m = -1e30f, l = 0.f;
    float a0 = 0.f, a1 = 0.f, a2 = 0.f, a3 = 0.f;

    const int s0 = off[node], s1 = off[node + 1];
    if (s0 < s1) {
        int s = csr_src[s0];
        ushort4 kw = ((const ushort4*)(kb + (size_t)s * 256))[lane];
        ushort4 vw = ((const ushort4*)(vb + (size_t)s * 256))[lane];
        for (int i = s0; i < s1; ++i) {
            // prefetch next edge's rows (clamped) to hide gather latency
            int sn = csr_src[(i + 1 < s1) ? i + 1 : i];
            ushort4 kn = ((const ushort4*)(kb + (size_t)sn * 256))[lane];
            ushort4 vn = ((const ushort4*)(vb + (size_t)sn * 256))[lane];

            float p = q0 * bf2f(kw.x) + q1 * bf2f(kw.y)
                    + q2 * bf2f(kw.z) + q3 * bf2f(kw.w);
            p += __shfl_xor(p, 1);
            p += __shfl_xor(p, 2);
            p += __shfl_xor(p, 4);
            p += __shfl_xor(p, 8);

            float nm = fmaxf(m, p);
            float c = __expf(m - nm);
            float e = __expf(p - nm);
            m = nm;
            l = l * c + e;
            a0 = a0 * c + e * bf2f(vw.x);
            a1 = a1 * c + e * bf2f(vw.y);
            a2 = a2 * c + e * bf2f(vw.z);
            a3 = a3 * c + e * bf2f(vw.w);
            kw = kn; vw = vn;
        }
    }

    const float inv = 1.f / (l + 1e-16f);
    a0 *= inv; a1 *= inv; a2 *= inv; a3 *= inv;

    // mean over heads: channels live at lanes {c4, c4+16, c4+32, c4+48}
    a0 += __shfl_xor(a0, 16); a0 += __shfl_xor(a0, 32);
    a1 += __shfl_xor(a1, 16); a1 += __shfl_xor(a1, 32);
    a2 += __shfl_xor(a2, 16); a2 += __shfl_xor(a2, 32);
    a3 += __shfl_xor(a3, 16); a3 += __shfl_xor(a3, 32);

    float4 sk = ((const float4*)(skip + (size_t)node * 64))[c4];
    float o0 = 0.25f * a0 + sk.x;
    float o1 = 0.25f * a1 + sk.y;
    float o2 = 0.25f * a2 + sk.z;
    float o3 = 0.25f * a3 + sk.w;

    // LayerNorm over 64 channels (held as 16 lanes x 4, dup'd across groups)
    float s = o0 + o1 + o2 + o3;
    s += __shfl_xor(s, 1); s += __shfl_xor(s, 2);
    s += __shfl_xor(s, 4); s += __shfl_xor(s, 8);
    const float mu = s * (1.f / 64.f);
    float d0 = o0 - mu, d1 = o1 - mu, d2 = o2 - mu, d3 = o3 - mu;
    float vs = d0 * d0 + d1 * d1 + d2 * d2 + d3 * d3;
    vs += __shfl_xor(vs, 1); vs += __shfl_xor(vs, 2);
    vs += __shfl_xor(vs, 4); vs += __shfl_xor(vs, 8);
    const float rs = rsqrtf(vs * (1.f / 64.f) + 1e-5f);

    float4 g4 = ((const float4*)lng)[c4];
    float4 b4 = ((const float4*)lnb)[c4];
    float y0 = d0 * rs * g4.x + b4.x;
    float y1 = d1 * rs * g4.y + b4.y;
    float y2 = d2 * rs * g4.z + b4.z;
    float y3 = d3 * rs * g4.w + b4.w;
    if (RELU) {
        y0 = fmaxf(y0, 0.f); y1 = fmaxf(y1, 0.f);
        y2 = fmaxf(y2, 0.f); y3 = fmaxf(y3, 0.f);
    }

    if (lane < 16) {
        if (BF16OUT) {
            ushort4 o;
            o.x = f2bf(y0); o.y = f2bf(y1); o.z = f2bf(y2); o.w = f2bf(y3);
            ((ushort4*)out_bf)[(size_t)node * 16 + c4] = o;
        } else {
            ((float4*)out_f)[(size_t)node * 16 + c4] =
                make_float4(y0, y1, y2, y3);
        }
    }
}

// ---------------------------------------------------------------------------
// Final Linear 64->32 (LN already applied by fused_attn<0,0>)
// ---------------------------------------------------------------------------
__global__ __launch_bounds__(256) void final_matvec(
    const float* __restrict__ y, const float* __restrict__ Wf,
    const float* __restrict__ bfv, float* __restrict__ out, int n)
{
    __shared__ float ys[8][64];
    int nb = blockIdx.x * 8;
    for (int i = threadIdx.x; i < 512; i += 256) {
        int r = i >> 6, c = i & 63;
        int gn = nb + r;
        ys[r][c] = (gn < n) ? y[(size_t)gn * 64 + c] : 0.f;
    }
    __syncthreads();
    int r = threadIdx.x >> 5, o = threadIdx.x & 31;
    int gn = nb + r;
    if (gn < n) {
        float a = bfv[o];
        #pragma unroll
        for (int c = 0; c < 64; ++c) a = fmaf(ys[r][c], Wf[c * 32 + o], a);
        out[(size_t)gn * 32 + o] = a;
    }
}

// ---------------------------------------------------------------------------
extern "C" void kernel_launch(void* const* d_in, const int* in_sizes, int n_in,
                              void* d_out, int out_size, void* d_ws, size_t ws_size,
                              hipStream_t stream)
{
    const float* x   = (const float*)d_in[0];
    const int*   ei  = (const int*)d_in[1];
    const float* Wq1 = (const float*)d_in[2];  const float* bq1 = (const float*)d_in[3];
    const float* Wk1 = (const float*)d_in[4];  const float* bk1 = (const float*)d_in[5];
    const float* Wv1 = (const float*)d_in[6];  const float* bv1 = (const float*)d_in[7];
    const float* Ws1 = (const float*)d_in[8];  const float* bs1 = (const float*)d_in[9];
    const float* Wq2 = (const float*)d_in[10]; const float* bq2 = (const float*)d_in[11];
    const float* Wk2 = (const float*)d_in[12]; const float* bk2 = (const float*)d_in[13];
    const float* Wv2 = (const float*)d_in[14]; const float* bv2 = (const float*)d_in[15];
    const float* Ws2 = (const float*)d_in[16]; const float* bs2 = (const float*)d_in[17];
    const float* lng = (const float*)d_in[18]; const float* lnb = (const float*)d_in[19];
    const float* Wf  = (const float*)d_in[20]; const float* bf  = (const float*)d_in[21];

    const int N = in_sizes[0] / 64;
    const int E = in_sizes[1] / 2;
    const int* src  = ei;
    const int* dstp = ei + E;

    char* p = (char*)d_ws;
    u16* qb   = (u16*)p; p += (size_t)N * 256 * 2;
    u16* kb   = (u16*)p; p += (size_t)N * 256 * 2;
    u16* vb   = (u16*)p; p += (size_t)N * 256 * 2;
    u16* xbf  = (u16*)p; p += (size_t)N * 64 * 2;   // conv1 in; conv1 out (h, bf16)
    u16* wt1  = (u16*)p; p += 832 * 64 * 2;
    u16* wt2  = (u16*)p; p += 832 * 64 * 2;
    float* ba1  = (float*)p; p += 832 * 4;
    float* ba2  = (float*)p; p += 832 * 4;
    float* skip = (float*)p; p += (size_t)N * 64 * 4;
    float* y2   = (float*)p; p += (size_t)N * 64 * 4;
    int* deg    = (int*)p; p += (size_t)N * 4;
    int* off    = (int*)p; p += ((size_t)N + 1) * 4;
    int* cursor = (int*)p; p += (size_t)N * 4;
    int* csr    = (int*)p; p += (size_t)E * 4;

    const int cvx_blocks  = (N * 16 + 255) / 256;     // N*64/4 elems
    const int cvw_blocks  = (832 * 64 + 255) / 256;
    const int e_blocks    = (E + 255) / 256;
    const int gemm_blocks = (N + 15) / 16;
    const int attn_blocks = (N + 3) / 4;
    const int fin_blocks  = (N + 7) / 8;

    // ---- prep: conversions + CSR ----
    convert_x<<<cvx_blocks, 256, 0, stream>>>(x, xbf, N * 16);
    convert_w<<<cvw_blocks, 256, 0, stream>>>(Wq1, Wk1, Wv1, Ws1, bq1, bk1, bv1, bs1, wt1, ba1);
    convert_w<<<cvw_blocks, 256, 0, stream>>>(Wq2, Wk2, Wv2, Ws2, bq2, bk2, bv2, bs2, wt2, ba2);
    hipMemsetAsync(deg, 0, (size_t)N * 4, stream);
    hist_kernel<<<e_blocks, 256, 0, stream>>>(dstp, deg, E);
    scan_kernel<<<1, 1024, 0, stream>>>(deg, off, cursor, N);
    fill_kernel<<<e_blocks, 256, 0, stream>>>(src, dstp, cursor, csr, E);

    // ---- conv1 ----
    gemm_qkvs<<<gemm_blocks, 256, 0, stream>>>(xbf, wt1, ba1, qb, kb, vb, skip, N);
    fused_attn<1, 1><<<attn_blocks, 256, 0, stream>>>(qb, kb, vb, skip, off, csr,
                                                      lng, lnb, xbf, nullptr, N);
    // ---- conv2 ----
    gemm_qkvs<<<gemm_blocks, 256, 0, stream>>>(xbf, wt2, ba2, qb, kb, vb, skip, N);
    fused_attn<0, 0><<<attn_blocks, 256, 0, stream>>>(qb, kb, vb, skip, off, csr,
                                                      lng, lnb, nullptr, y2, N);
    // ---- final linear ----
    final_matvec<<<fin_blocks, 256, 0, stream>>>(y2, Wf, bf, (float*)d_out, N);
}

// Round 4
// 466.502 us; speedup vs baseline: 2.9963x; 1.2887x over previous
//
#include <hip/hip_runtime.h>
#include <hip/hip_bf16.h>
#include <math.h>

typedef unsigned short u16;
typedef __attribute__((ext_vector_type(8))) short bf16x8;
typedef __attribute__((ext_vector_type(4))) float f32x4;

__device__ __forceinline__ u16 f2bf(float f) {
    unsigned u = __float_as_uint(f);
    u += 0x7fffu + ((u >> 16) & 1u);   // RNE
    return (u16)(u >> 16);
}
__device__ __forceinline__ float bf2f(u16 h) {
    return __uint_as_float(((unsigned)h) << 16);
}

// ---------------------------------------------------------------------------
// fp32 -> bf16 conversion of X (N*64 elems), float4 -> ushort4
// ---------------------------------------------------------------------------
__global__ __launch_bounds__(256) void convert_x(
    const float* __restrict__ x, u16* __restrict__ xbf, int total4)
{
    int i = blockIdx.x * 256 + threadIdx.x;
    if (i >= total4) return;
    float4 v = ((const float4*)x)[i];
    ushort4 o;
    o.x = f2bf(v.x); o.y = f2bf(v.y); o.z = f2bf(v.z); o.w = f2bf(v.w);
    ((ushort4*)xbf)[i] = o;
}

// ---------------------------------------------------------------------------
// Build transposed bf16 weight block wt[832][64] (cols: 0-255 q, 256-511 k,
// 512-767 v, 768-831 s) + concatenated fp32 bias ba[832].
// ---------------------------------------------------------------------------
__global__ __launch_bounds__(256) void convert_w(
    const float* __restrict__ Wq, const float* __restrict__ Wk,
    const float* __restrict__ Wv, const float* __restrict__ Ws,
    const float* __restrict__ bq, const float* __restrict__ bk,
    const float* __restrict__ bv, const float* __restrict__ bs,
    u16* __restrict__ wt, float* __restrict__ ba)
{
    int idx = blockIdx.x * 256 + threadIdx.x;
    if (idx >= 832 * 64) return;
    int col = idx >> 6, k = idx & 63;
    float w;
    if      (col < 256) w = Wq[k * 256 + col];
    else if (col < 512) w = Wk[k * 256 + (col - 256)];
    else if (col < 768) w = Wv[k * 256 + (col - 512)];
    else                w = Ws[k * 64  + (col - 768)];
    wt[col * 64 + k] = f2bf(w);
    if (k == 0)
        ba[col] = (col < 256) ? bq[col] : (col < 512) ? bk[col - 256]
                 : (col < 768) ? bv[col - 512] : bs[col - 768];
}

// ---------------------------------------------------------------------------
// CSR build: histogram, 3-phase coalesced scan, fill
// ---------------------------------------------------------------------------
__global__ __launch_bounds__(256) void hist_kernel(
    const int* __restrict__ dst, int* __restrict__ deg, int E)
{
    int e = blockIdx.x * 256 + threadIdx.x;
    if (e < E) atomicAdd(&deg[dst[e]], 1);
}

// phase A: per-block sum of 256 deg entries (coalesced)
__global__ __launch_bounds__(256) void scanA(
    const int* __restrict__ deg, int* __restrict__ bsum, int n)
{
    int i = blockIdx.x * 256 + threadIdx.x;
    int v = (i < n) ? deg[i] : 0;
    #pragma unroll
    for (int o = 32; o; o >>= 1) v += __shfl_xor(v, o);
    __shared__ int wsum[4];
    if ((threadIdx.x & 63) == 0) wsum[threadIdx.x >> 6] = v;
    __syncthreads();
    if (threadIdx.x == 0)
        bsum[blockIdx.x] = wsum[0] + wsum[1] + wsum[2] + wsum[3];
}

// phase B: exclusive scan of block sums (nb <= 256), one block
__global__ __launch_bounds__(256) void scanB(
    const int* __restrict__ bsum, int* __restrict__ bpre, int nb)
{
    int t = threadIdx.x;
    int v = (t < nb) ? bsum[t] : 0;
    int lane = t & 63, wv = t >> 6;
    int sv = v;
    #pragma unroll
    for (int o = 1; o < 64; o <<= 1) {
        int u = __shfl_up(sv, o);
        if (lane >= o) sv += u;
    }
    __shared__ int wsum[4];
    if (lane == 63) wsum[wv] = sv;
    __syncthreads();
    int add = 0;
    for (int k = 0; k < wv; ++k) add += wsum[k];
    if (t < nb) bpre[t] = sv + add - v;   // exclusive
}

// phase C: per-block exclusive scan + base; writes off[] and cursor[]
__global__ __launch_bounds__(256) void scanC(
    const int* __restrict__ deg, const int* __restrict__ bpre,
    int* __restrict__ off, int* __restrict__ cursor, int n, int E)
{
    int i = blockIdx.x * 256 + threadIdx.x;
    int v = (i < n) ? deg[i] : 0;
    int lane = threadIdx.x & 63, wv = threadIdx.x >> 6;
    int sv = v;
    #pragma unroll
    for (int o = 1; o < 64; o <<= 1) {
        int u = __shfl_up(sv, o);
        if (lane >= o) sv += u;
    }
    __shared__ int wsum[4];
    if (lane == 63) wsum[wv] = sv;
    __syncthreads();
    int add = bpre[blockIdx.x];
    for (int k = 0; k < wv; ++k) add += wsum[k];
    int excl = add + sv - v;
    if (i < n) {
        off[i] = excl; cursor[i] = excl;
        if (i == n - 1) off[n] = E;
    }
}

__global__ __launch_bounds__(256) void fill_kernel(
    const int* __restrict__ src, const int* __restrict__ dst,
    int* __restrict__ cursor, int* __restrict__ csr_src, int E)
{
    int e = blockIdx.x * 256 + threadIdx.x;
    if (e >= E) return;
    int slot = atomicAdd(&cursor[dst[e]], 1);
    csr_src[slot] = src[e];
}

// ---------------------------------------------------------------------------
// bf16 MFMA GEMM, W as A-operand / X as B-operand so each lane owns 4
// CONSECUTIVE output cols of one node: packed ushort4/float4 stores.
// D[lane,reg]: node = node0 + (lane&15); col = tile*16 + (lane>>4)*4 + reg.
// ---------------------------------------------------------------------------
__global__ __launch_bounds__(256) void gemm_qkvs(
    const u16* __restrict__ xbf, const u16* __restrict__ wt,
    const float* __restrict__ ba,
    u16* __restrict__ qb, u16* __restrict__ kb, u16* __restrict__ vb,
    float* __restrict__ skip, int n)
{
    const int w = threadIdx.x >> 6, lane = threadIdx.x & 63;
    const int r = lane & 15, g = lane >> 4;
    const int node0 = blockIdx.x * 16;

    int nr = node0 + r; if (nr >= n) nr = n - 1;
    const u16* xr = xbf + (size_t)nr * 64 + g * 8;
    bf16x8 b0 = *(const bf16x8*)xr;          // X fragment (B operand)
    bf16x8 b1 = *(const bf16x8*)(xr + 32);

    const int colbase = w * 208;
    const int node = node0 + r;
    for (int ct = 0; ct < 13; ++ct) {
        int colr = colbase + ct * 16 + r;    // wt row for A fragment
        const u16* wr = wt + (size_t)colr * 64 + g * 8;
        bf16x8 a0 = *(const bf16x8*)wr;
        bf16x8 a1 = *(const bf16x8*)(wr + 32);
        f32x4 acc = {0.f, 0.f, 0.f, 0.f};
        acc = __builtin_amdgcn_mfma_f32_16x16x32_bf16(a0, b0, acc, 0, 0, 0);
        acc = __builtin_amdgcn_mfma_f32_16x16x32_bf16(a1, b1, acc, 0, 0, 0);
        int col0 = colbase + ct * 16 + g * 4;
        float4 bias = *(const float4*)(ba + col0);
        if (node < n) {
            float v0 = acc[0] + bias.x, v1 = acc[1] + bias.y;
            float v2 = acc[2] + bias.z, v3 = acc[3] + bias.w;
            if (col0 < 768) {
                int which = col0 >> 8, c = col0 & 255;
                u16* dp = (which == 0) ? qb : (which == 1) ? kb : vb;
                ushort4 o;
                o.x = f2bf(v0); o.y = f2bf(v1); o.z = f2bf(v2); o.w = f2bf(v3);
                *(ushort4*)(dp + (size_t)node * 256 + c) = o;
            } else {
                *(float4*)(skip + (size_t)node * 64 + (col0 - 768)) =
                    make_float4(v0, v1, v2, v3);
            }
        }
    }
}

// ---------------------------------------------------------------------------
// Fused attention: TWO nodes per wave (half-wave each), online softmax.
// Lane: half = lane>>5 (node select), hl = lane&31 = h*8 + c8; lane holds
// 8 channels (h*64 + c8*8..+7) -> one 16B dwordx4 per k/v row per lane.
// Dot reduce: 3 shfl_xor per iteration covering both nodes' edges.
// Prefetch depth 2 (8 row-gathers in flight). Epilogue (head-mean via
// xor 8/16, skip, LN(+ReLU)) shared by both nodes.
// ---------------------------------------------------------------------------
template <int RELU, int BF16OUT>
__global__ __launch_bounds__(256) void fused_attn(
    const u16* __restrict__ qb, const u16* __restrict__ kb,
    const u16* __restrict__ vb, const float* __restrict__ skip,
    const int* __restrict__ off, const int* __restrict__ csr,
    const float* __restrict__ lng, const float* __restrict__ lnb,
    u16* __restrict__ out_bf, float* __restrict__ out_f, int n)
{
    const int lane = threadIdx.x & 63;
    const int half = lane >> 5;
    const int hl   = lane & 31;
    const int c8   = lane & 7;
    const int pair = blockIdx.x * 4 + (threadIdx.x >> 6);
    const int node = pair * 2 + half;
    const bool nvalid = node < n;
    const int nodeC = nvalid ? node : n - 1;

    const bf16x8 qv = *(const bf16x8*)(qb + (size_t)nodeC * 256 + hl * 8);
    float qf[8];
    #pragma unroll
    for (int j = 0; j < 8; ++j) qf[j] = bf2f((u16)qv[j]) * 0.125f;

    const int s0 = off[nodeC], s1 = off[nodeC + 1];
    const int deg = nvalid ? (s1 - s0) : 0;
    int to = __shfl_xor(deg, 32);
    const int tmax = max(deg, to);

    float m = -1e30f, l = 0.f;
    float a[8] = {0.f, 0.f, 0.f, 0.f, 0.f, 0.f, 0.f, 0.f};

    if (tmax > 0) {
        // clamped CSR index: repeats last own edge (masked) or csr[0] if empty
        #define SRC_AT(t) csr[(deg > 0) ? min(s0 + (t), s1 - 1) : 0]
        int sA = SRC_AT(0);
        bf16x8 k0 = *(const bf16x8*)(kb + (size_t)sA * 256 + hl * 8);
        bf16x8 v0 = *(const bf16x8*)(vb + (size_t)sA * 256 + hl * 8);
        int sB = SRC_AT(tmax > 1 ? 1 : 0);
        bf16x8 k1 = *(const bf16x8*)(kb + (size_t)sB * 256 + hl * 8);
        bf16x8 v1 = *(const bf16x8*)(vb + (size_t)sB * 256 + hl * 8);

        #pragma unroll 2
        for (int t = 0; t < tmax; ++t) {
            int tp = (t + 2 < tmax) ? t + 2 : tmax - 1;
            int sn = SRC_AT(tp);
            bf16x8 kn = *(const bf16x8*)(kb + (size_t)sn * 256 + hl * 8);
            bf16x8 vn = *(const bf16x8*)(vb + (size_t)sn * 256 + hl * 8);

            float p = 0.f;
            #pragma unroll
            for (int j = 0; j < 8; ++j) p = fmaf(qf[j], bf2f((u16)k0[j]), p);
            p += __shfl_xor(p, 1);
            p += __shfl_xor(p, 2);
            p += __shfl_xor(p, 4);
            p = (t < deg) ? p : -2e30f;     // mask tail / shorter half

            float nm = fmaxf(m, p);
            float c = __expf(m - nm);
            float e = __expf(p - nm);
            m = nm;
            l = l * c + e;
            #pragma unroll
            for (int j = 0; j < 8; ++j)
                a[j] = fmaf(e, bf2f((u16)v0[j]), a[j] * c);

            k0 = k1; v0 = v1; k1 = kn; v1 = vn;
        }
        #undef SRC_AT
    }

    // normalize per head, then mean over heads (hl bits 3,4)
    const float inv = 0.25f / (l + 1e-16f);
    #pragma unroll
    for (int j = 0; j < 8; ++j) {
        a[j] *= inv;
        a[j] += __shfl_xor(a[j], 8);
        a[j] += __shfl_xor(a[j], 16);
    }

    // skip connection: channels c8*8 .. +7
    const float4* skp = (const float4*)(skip + (size_t)nodeC * 64 + c8 * 8);
    float4 sk0 = skp[0], sk1 = skp[1];
    float o[8];
    o[0] = a[0] + sk0.x; o[1] = a[1] + sk0.y;
    o[2] = a[2] + sk0.z; o[3] = a[3] + sk0.w;
    o[4] = a[4] + sk1.x; o[5] = a[5] + sk1.y;
    o[6] = a[6] + sk1.z; o[7] = a[7] + sk1.w;

    // LayerNorm over 64 channels (8 lanes x 8 ch within each half)
    float s = o[0] + o[1] + o[2] + o[3] + o[4] + o[5] + o[6] + o[7];
    s += __shfl_xor(s, 1); s += __shfl_xor(s, 2); s += __shfl_xor(s, 4);
    const float mu = s * (1.f / 64.f);
    float vs = 0.f;
    #pragma unroll
    for (int j = 0; j < 8; ++j) { o[j] -= mu; vs = fmaf(o[j], o[j], vs); }
    vs += __shfl_xor(vs, 1); vs += __shfl_xor(vs, 2); vs += __shfl_xor(vs, 4);
    const float rs = rsqrtf(vs * (1.f / 64.f) + 1e-5f);

    const float4* gp = (const float4*)(lng + c8 * 8);
    const float4* bp = (const float4*)(lnb + c8 * 8);
    float4 g0 = gp[0], g1 = gp[1], b0 = bp[0], b1 = bp[1];
    float y[8];
    y[0] = o[0] * rs * g0.x + b0.x; y[1] = o[1] * rs * g0.y + b0.y;
    y[2] = o[2] * rs * g0.z + b0.z; y[3] = o[3] * rs * g0.w + b0.w;
    y[4] = o[4] * rs * g1.x + b1.x; y[5] = o[5] * rs * g1.y + b1.y;
    y[6] = o[6] * rs * g1.z + b1.z; y[7] = o[7] * rs * g1.w + b1.w;
    if (RELU) {
        #pragma unroll
        for (int j = 0; j < 8; ++j) y[j] = fmaxf(y[j], 0.f);
    }

    if (hl < 8 && nvalid) {            // h==0 lanes of each half store
        if (BF16OUT) {
            bf16x8 ob;
            #pragma unroll
            for (int j = 0; j < 8; ++j) ob[j] = (short)f2bf(y[j]);
            *(bf16x8*)(out_bf + (size_t)node * 64 + c8 * 8) = ob;
        } else {
            float4* op = (float4*)(out_f + (size_t)node * 64 + c8 * 8);
            op[0] = make_float4(y[0], y[1], y[2], y[3]);
            op[1] = make_float4(y[4], y[5], y[6], y[7]);
        }
    }
}

// ---------------------------------------------------------------------------
// Final Linear 64->32 (LN already applied by fused_attn<0,0>)
// ---------------------------------------------------------------------------
__global__ __launch_bounds__(256) void final_matvec(
    const float* __restrict__ y, const float* __restrict__ Wf,
    const float* __restrict__ bfv, float* __restrict__ out, int n)
{
    __shared__ float ys[8][64];
    int nb = blockIdx.x * 8;
    for (int i = threadIdx.x; i < 512; i += 256) {
        int r = i >> 6, c = i & 63;
        int gn = nb + r;
        ys[r][c] = (gn < n) ? y[(size_t)gn * 64 + c] : 0.f;
    }
    __syncthreads();
    int r = threadIdx.x >> 5, o = threadIdx.x & 31;
    int gn = nb + r;
    if (gn < n) {
        float a = bfv[o];
        #pragma unroll
        for (int c = 0; c < 64; ++c) a = fmaf(ys[r][c], Wf[c * 32 + o], a);
        out[(size_t)gn * 32 + o] = a;
    }
}

// ---------------------------------------------------------------------------
extern "C" void kernel_launch(void* const* d_in, const int* in_sizes, int n_in,
                              void* d_out, int out_size, void* d_ws, size_t ws_size,
                              hipStream_t stream)
{
    const float* x   = (const float*)d_in[0];
    const int*   ei  = (const int*)d_in[1];
    const float* Wq1 = (const float*)d_in[2];  const float* bq1 = (const float*)d_in[3];
    const float* Wk1 = (const float*)d_in[4];  const float* bk1 = (const float*)d_in[5];
    const float* Wv1 = (const float*)d_in[6];  const float* bv1 = (const float*)d_in[7];
    const float* Ws1 = (const float*)d_in[8];  const float* bs1 = (const float*)d_in[9];
    const float* Wq2 = (const float*)d_in[10]; const float* bq2 = (const float*)d_in[11];
    const float* Wk2 = (const float*)d_in[12]; const float* bk2 = (const float*)d_in[13];
    const float* Wv2 = (const float*)d_in[14]; const float* bv2 = (const float*)d_in[15];
    const float* Ws2 = (const float*)d_in[16]; const float* bs2 = (const float*)d_in[17];
    const float* lng = (const float*)d_in[18]; const float* lnb = (const float*)d_in[19];
    const float* Wf  = (const float*)d_in[20]; const float* bf  = (const float*)d_in[21];

    const int N = in_sizes[0] / 64;
    const int E = in_sizes[1] / 2;
    const int* src  = ei;
    const int* dstp = ei + E;

    char* p = (char*)d_ws;
    u16* qb   = (u16*)p; p += (size_t)N * 256 * 2;
    u16* kb   = (u16*)p; p += (size_t)N * 256 * 2;
    u16* vb   = (u16*)p; p += (size_t)N * 256 * 2;
    u16* xbf  = (u16*)p; p += (size_t)N * 64 * 2;   // conv1 in; conv1 out (bf16)
    u16* wt1  = (u16*)p; p += 832 * 64 * 2;
    u16* wt2  = (u16*)p; p += 832 * 64 * 2;
    float* ba1  = (float*)p; p += 832 * 4;
    float* ba2  = (float*)p; p += 832 * 4;
    float* skip = (float*)p; p += (size_t)N * 64 * 4;
    float* y2   = (float*)p; p += (size_t)N * 64 * 4;
    int* deg    = (int*)p; p += (size_t)N * 4;
    int* off    = (int*)p; p += ((size_t)N + 1) * 4;
    int* cursor = (int*)p; p += (size_t)N * 4;
    int* csr    = (int*)p; p += (size_t)E * 4;
    int* bsum   = (int*)p; p += 1024;
    int* bpre   = (int*)p; p += 1024;

    const int cvx_blocks  = (N * 16 + 255) / 256;
    const int cvw_blocks  = (832 * 64 + 255) / 256;
    const int e_blocks    = (E + 255) / 256;
    const int n_blocks    = (N + 255) / 256;        // scan phases (<=256 blocks)
    const int gemm_blocks = (N + 15) / 16;
    const int attn_blocks = ((N + 1) / 2 + 3) / 4;  // 2 nodes/wave, 4 waves/blk
    const int fin_blocks  = (N + 7) / 8;

    // ---- prep: conversions + CSR ----
    convert_x<<<cvx_blocks, 256, 0, stream>>>(x, xbf, N * 16);
    convert_w<<<cvw_blocks, 256, 0, stream>>>(Wq1, Wk1, Wv1, Ws1, bq1, bk1, bv1, bs1, wt1, ba1);
    convert_w<<<cvw_blocks, 256, 0, stream>>>(Wq2, Wk2, Wv2, Ws2, bq2, bk2, bv2, bs2, wt2, ba2);
    hipMemsetAsync(deg, 0, (size_t)N * 4, stream);
    hist_kernel<<<e_blocks, 256, 0, stream>>>(dstp, deg, E);
    scanA<<<n_blocks, 256, 0, stream>>>(deg, bsum, N);
    scanB<<<1, 256, 0, stream>>>(bsum, bpre, n_blocks);
    scanC<<<n_blocks, 256, 0, stream>>>(deg, bpre, off, cursor, N, E);
    fill_kernel<<<e_blocks, 256, 0, stream>>>(src, dstp, cursor, csr, E);

    // ---- conv1 ----
    gemm_qkvs<<<gemm_blocks, 256, 0, stream>>>(xbf, wt1, ba1, qb, kb, vb, skip, N);
    fused_attn<1, 1><<<attn_blocks, 256, 0, stream>>>(qb, kb, vb, skip, off, csr,
                                                      lng, lnb, xbf, nullptr, N);
    // ---- conv2 ----
    gemm_qkvs<<<gemm_blocks, 256, 0, stream>>>(xbf, wt2, ba2, qb, kb, vb, skip, N);
    fused_attn<0, 0><<<attn_blocks, 256, 0, stream>>>(qb, kb, vb, skip, off, csr,
                                                      lng, lnb, nullptr, y2, N);
    // ---- final linear ----
    final_matvec<<<fin_blocks, 256, 0, stream>>>(y2, Wf, bf, (float*)d_out, N);
}

// Round 5
// 452.153 us; speedup vs baseline: 3.0914x; 1.0317x over previous
//
#include <hip/hip_runtime.h>
#include <hip/hip_bf16.h>
#include <math.h>

typedef unsigned short u16;
typedef __attribute__((ext_vector_type(8))) short bf16x8;
typedef __attribute__((ext_vector_type(4))) float f32x4;

__device__ __forceinline__ u16 f2bf(float f) {
    unsigned u = __float_as_uint(f);
    u += 0x7fffu + ((u >> 16) & 1u);   // RNE
    return (u16)(u >> 16);
}
__device__ __forceinline__ float bf2f(u16 h) {
    return __uint_as_float(((unsigned)h) << 16);
}

// ---------------------------------------------------------------------------
// Build transposed bf16 weight block wt[832][64] (cols: 0-255 q, 256-511 k,
// 512-767 v, 768-831 s) + concatenated fp32 bias ba[832].
// ---------------------------------------------------------------------------
__global__ __launch_bounds__(256) void convert_w(
    const float* __restrict__ Wq, const float* __restrict__ Wk,
    const float* __restrict__ Wv, const float* __restrict__ Ws,
    const float* __restrict__ bq, const float* __restrict__ bk,
    const float* __restrict__ bv, const float* __restrict__ bs,
    u16* __restrict__ wt, float* __restrict__ ba)
{
    int idx = blockIdx.x * 256 + threadIdx.x;
    if (idx >= 832 * 64) return;
    int col = idx >> 6, k = idx & 63;
    float w;
    if      (col < 256) w = Wq[k * 256 + col];
    else if (col < 512) w = Wk[k * 256 + (col - 256)];
    else if (col < 768) w = Wv[k * 256 + (col - 512)];
    else                w = Ws[k * 64  + (col - 768)];
    wt[col * 64 + k] = f2bf(w);
    if (k == 0)
        ba[col] = (col < 256) ? bq[col] : (col < 512) ? bk[col - 256]
                 : (col < 768) ? bv[col - 512] : bs[col - 768];
}

// ---------------------------------------------------------------------------
// CSR build: histogram, 3-phase coalesced scan, fill
// ---------------------------------------------------------------------------
__global__ __launch_bounds__(256) void hist_kernel(
    const int* __restrict__ dst, int* __restrict__ deg, int E)
{
    int e = blockIdx.x * 256 + threadIdx.x;
    if (e < E) atomicAdd(&deg[dst[e]], 1);
}

__global__ __launch_bounds__(256) void scanA(
    const int* __restrict__ deg, int* __restrict__ bsum, int n)
{
    int i = blockIdx.x * 256 + threadIdx.x;
    int v = (i < n) ? deg[i] : 0;
    #pragma unroll
    for (int o = 32; o; o >>= 1) v += __shfl_xor(v, o);
    __shared__ int wsum[4];
    if ((threadIdx.x & 63) == 0) wsum[threadIdx.x >> 6] = v;
    __syncthreads();
    if (threadIdx.x == 0)
        bsum[blockIdx.x] = wsum[0] + wsum[1] + wsum[2] + wsum[3];
}

__global__ __launch_bounds__(256) void scanB(
    const int* __restrict__ bsum, int* __restrict__ bpre, int nb)
{
    int t = threadIdx.x;
    int v = (t < nb) ? bsum[t] : 0;
    int lane = t & 63, wv = t >> 6;
    int sv = v;
    #pragma unroll
    for (int o = 1; o < 64; o <<= 1) {
        int u = __shfl_up(sv, o);
        if (lane >= o) sv += u;
    }
    __shared__ int wsum[4];
    if (lane == 63) wsum[wv] = sv;
    __syncthreads();
    int add = 0;
    for (int k = 0; k < wv; ++k) add += wsum[k];
    if (t < nb) bpre[t] = sv + add - v;   // exclusive
}

__global__ __launch_bounds__(256) void scanC(
    const int* __restrict__ deg, const int* __restrict__ bpre,
    int* __restrict__ off, int* __restrict__ cursor, int n, int E)
{
    int i = blockIdx.x * 256 + threadIdx.x;
    int v = (i < n) ? deg[i] : 0;
    int lane = threadIdx.x & 63, wv = threadIdx.x >> 6;
    int sv = v;
    #pragma unroll
    for (int o = 1; o < 64; o <<= 1) {
        int u = __shfl_up(sv, o);
        if (lane >= o) sv += u;
    }
    __shared__ int wsum[4];
    if (lane == 63) wsum[wv] = sv;
    __syncthreads();
    int add = bpre[blockIdx.x];
    for (int k = 0; k < wv; ++k) add += wsum[k];
    int excl = add + sv - v;
    if (i < n) {
        off[i] = excl; cursor[i] = excl;
        if (i == n - 1) off[n] = E;
    }
}

__global__ __launch_bounds__(256) void fill_kernel(
    const int* __restrict__ src, const int* __restrict__ dst,
    int* __restrict__ cursor, int* __restrict__ csr_src, int E)
{
    int e = blockIdx.x * 256 + threadIdx.x;
    if (e >= E) return;
    int slot = atomicAdd(&cursor[dst[e]], 1);
    csr_src[slot] = src[e];
}

// ---------------------------------------------------------------------------
// bf16 MFMA GEMM, W as A-operand / X as B-operand; each lane owns 4
// consecutive output cols of one node (packed ushort4/float4 stores).
// FP32IN: read fp32 X and convert in-register (folds convert_x away).
// A-fragments for tile ct+1 are prefetched before the MFMAs of tile ct.
// ---------------------------------------------------------------------------
template <int FP32IN>
__global__ __launch_bounds__(256) void gemm_qkvs(
    const void* __restrict__ Xv, const u16* __restrict__ wt,
    const float* __restrict__ ba,
    u16* __restrict__ qb, u16* __restrict__ kb, u16* __restrict__ vb,
    float* __restrict__ skip, int n)
{
    const int w = threadIdx.x >> 6, lane = threadIdx.x & 63;
    const int r = lane & 15, g = lane >> 4;
    const int node0 = blockIdx.x * 16;

    int nr = node0 + r; if (nr >= n) nr = n - 1;
    bf16x8 b0, b1;                            // X fragment (B operand)
    if (FP32IN) {
        const float* xr = (const float*)Xv + (size_t)nr * 64 + g * 8;
        float t0[8], t1[8];
        *(float4*)(t0)     = ((const float4*)xr)[0];
        *(float4*)(t0 + 4) = ((const float4*)xr)[1];
        *(float4*)(t1)     = ((const float4*)(xr + 32))[0];
        *(float4*)(t1 + 4) = ((const float4*)(xr + 32))[1];
        #pragma unroll
        for (int j = 0; j < 8; ++j) {
            b0[j] = (short)f2bf(t0[j]);
            b1[j] = (short)f2bf(t1[j]);
        }
    } else {
        const u16* xr = (const u16*)Xv + (size_t)nr * 64 + g * 8;
        b0 = *(const bf16x8*)xr;
        b1 = *(const bf16x8*)(xr + 32);
    }

    const int colbase = w * 208;
    const int node = node0 + r;

    const u16* wr0 = wt + (size_t)(colbase + r) * 64 + g * 8;
    bf16x8 a0 = *(const bf16x8*)wr0;
    bf16x8 a1 = *(const bf16x8*)(wr0 + 32);

    for (int ct = 0; ct < 13; ++ct) {
        // prefetch next tile's A fragments
        int ctn = (ct + 1 < 13) ? ct + 1 : 12;
        const u16* wrn = wt + (size_t)(colbase + ctn * 16 + r) * 64 + g * 8;
        bf16x8 an0 = *(const bf16x8*)wrn;
        bf16x8 an1 = *(const bf16x8*)(wrn + 32);

        f32x4 acc = {0.f, 0.f, 0.f, 0.f};
        acc = __builtin_amdgcn_mfma_f32_16x16x32_bf16(a0, b0, acc, 0, 0, 0);
        acc = __builtin_amdgcn_mfma_f32_16x16x32_bf16(a1, b1, acc, 0, 0, 0);
        int col0 = colbase + ct * 16 + g * 4;
        float4 bias = *(const float4*)(ba + col0);
        if (node < n) {
            float v0 = acc[0] + bias.x, v1 = acc[1] + bias.y;
            float v2 = acc[2] + bias.z, v3 = acc[3] + bias.w;
            if (col0 < 768) {
                int which = col0 >> 8, c = col0 & 255;
                u16* dp = (which == 0) ? qb : (which == 1) ? kb : vb;
                ushort4 o;
                o.x = f2bf(v0); o.y = f2bf(v1); o.z = f2bf(v2); o.w = f2bf(v3);
                *(ushort4*)(dp + (size_t)node * 256 + c) = o;
            } else {
                *(float4*)(skip + (size_t)node * 64 + (col0 - 768)) =
                    make_float4(v0, v1, v2, v3);
            }
        }
        a0 = an0; a1 = an1;
    }
}

// ---------------------------------------------------------------------------
// Fused attention: ONE node per wave, TWO edge-streams (half-wave each:
// stream h processes edges t = 2i+h with its own online-softmax state;
// states merged at the end via shfl_xor 32). hl = lane&31 = h*8+c8 holds
// 8 channels -> one 16B dwordx4 per k/v row per lane. Prefetch depth 3
// (6 row-gathers in flight/wave). Epilogue: merge + head-mean + skip +
// LN(+ReLU), computed redundantly, stored by lanes 0..7.
// ---------------------------------------------------------------------------
template <int RELU, int BF16OUT>
__global__ __launch_bounds__(256) void fused_attn(
    const u16* __restrict__ qb, const u16* __restrict__ kb,
    const u16* __restrict__ vb, const float* __restrict__ skip,
    const int* __restrict__ off, const int* __restrict__ csr,
    const float* __restrict__ lng, const float* __restrict__ lnb,
    u16* __restrict__ out_bf, float* __restrict__ out_f, int n)
{
    const int lane = threadIdx.x & 63;
    const int half = lane >> 5;          // edge-stream parity
    const int hl   = lane & 31;         // h*8 + c8
    const int c8   = lane & 7;
    const int node = blockIdx.x * 4 + (threadIdx.x >> 6);
    const bool nvalid = node < n;
    const int nodeC = nvalid ? node : n - 1;

    const bf16x8 qv = *(const bf16x8*)(qb + (size_t)nodeC * 256 + hl * 8);
    float qf[8];
    #pragma unroll
    for (int j = 0; j < 8; ++j) qf[j] = bf2f((u16)qv[j]) * 0.125f;

    const int s0 = off[nodeC], s1 = off[nodeC + 1];
    const int deg = nvalid ? (s1 - s0) : 0;
    const int imax = (deg + 1) >> 1;     // iterations per stream

    float m = -1e30f, l = 0.f;
    float a[8] = {0.f, 0.f, 0.f, 0.f, 0.f, 0.f, 0.f, 0.f};

    if (imax > 0) {
        #define LOADKV(I, K, V) { \
            int _t = 2 * (I) + half; \
            int _ix = min(s0 + _t, s1 - 1); \
            int _s = csr[_ix]; \
            K = *(const bf16x8*)(kb + (size_t)_s * 256 + hl * 8); \
            V = *(const bf16x8*)(vb + (size_t)_s * 256 + hl * 8); }

        bf16x8 k0, v0, k1, v1, k2, v2;
        LOADKV(0, k0, v0);
        LOADKV(min(1, imax - 1), k1, v1);
        LOADKV(min(2, imax - 1), k2, v2);

        #pragma unroll 3
        for (int i = 0; i < imax; ++i) {
            bf16x8 kn, vn;
            LOADKV(min(i + 3, imax - 1), kn, vn);

            float p = 0.f;
            #pragma unroll
            for (int j = 0; j < 8; ++j) p = fmaf(qf[j], bf2f((u16)k0[j]), p);
            p += __shfl_xor(p, 1);
            p += __shfl_xor(p, 2);
            p += __shfl_xor(p, 4);
            p = (2 * i + half < deg) ? p : -2e30f;   // tail mask

            float nm = fmaxf(m, p);
            float c = __expf(m - nm);
            float e = __expf(p - nm);
            m = nm;
            l = l * c + e;
            #pragma unroll
            for (int j = 0; j < 8; ++j)
                a[j] = fmaf(e, bf2f((u16)v0[j]), a[j] * c);

            k0 = k1; v0 = v1; k1 = k2; v1 = v2; k2 = kn; v2 = vn;
        }
        #undef LOADKV
    }

    // merge the two streams (lane ^ 32 holds the partner state)
    {
        float mo = __shfl_xor(m, 32);
        float lo_ = __shfl_xor(l, 32);
        float nm = fmaxf(m, mo);
        float c  = __expf(m - nm);
        float co = __expf(mo - nm);
        l = l * c + lo_ * co;
        #pragma unroll
        for (int j = 0; j < 8; ++j) {
            float ao = __shfl_xor(a[j], 32);
            a[j] = a[j] * c + ao * co;
        }
        m = nm;
    }

    // normalize per head, then mean over heads (hl bits 3,4)
    const float inv = 0.25f / (l + 1e-16f);
    #pragma unroll
    for (int j = 0; j < 8; ++j) {
        a[j] *= inv;
        a[j] += __shfl_xor(a[j], 8);
        a[j] += __shfl_xor(a[j], 16);
    }

    // skip connection: channels c8*8 .. +7
    const float4* skp = (const float4*)(skip + (size_t)nodeC * 64 + c8 * 8);
    float4 sk0 = skp[0], sk1 = skp[1];
    float o[8];
    o[0] = a[0] + sk0.x; o[1] = a[1] + sk0.y;
    o[2] = a[2] + sk0.z; o[3] = a[3] + sk0.w;
    o[4] = a[4] + sk1.x; o[5] = a[5] + sk1.y;
    o[6] = a[6] + sk1.z; o[7] = a[7] + sk1.w;

    // LayerNorm over 64 channels (8 lanes x 8 ch within each 8-lane group)
    float s = o[0] + o[1] + o[2] + o[3] + o[4] + o[5] + o[6] + o[7];
    s += __shfl_xor(s, 1); s += __shfl_xor(s, 2); s += __shfl_xor(s, 4);
    const float mu = s * (1.f / 64.f);
    float vs = 0.f;
    #pragma unroll
    for (int j = 0; j < 8; ++j) { o[j] -= mu; vs = fmaf(o[j], o[j], vs); }
    vs += __shfl_xor(vs, 1); vs += __shfl_xor(vs, 2); vs += __shfl_xor(vs, 4);
    const float rs = rsqrtf(vs * (1.f / 64.f) + 1e-5f);

    const float4* gp = (const float4*)(lng + c8 * 8);
    const float4* bp = (const float4*)(lnb + c8 * 8);
    float4 g0 = gp[0], g1 = gp[1], b0 = bp[0], b1 = bp[1];
    float y[8];
    y[0] = o[0] * rs * g0.x + b0.x; y[1] = o[1] * rs * g0.y + b0.y;
    y[2] = o[2] * rs * g0.z + b0.z; y[3] = o[3] * rs * g0.w + b0.w;
    y[4] = o[4] * rs * g1.x + b1.x; y[5] = o[5] * rs * g1.y + b1.y;
    y[6] = o[6] * rs * g1.z + b1.z; y[7] = o[7] * rs * g1.w + b1.w;
    if (RELU) {
        #pragma unroll
        for (int j = 0; j < 8; ++j) y[j] = fmaxf(y[j], 0.f);
    }

    if (lane < 8 && nvalid) {
        if (BF16OUT) {
            bf16x8 ob;
            #pragma unroll
            for (int j = 0; j < 8; ++j) ob[j] = (short)f2bf(y[j]);
            *(bf16x8*)(out_bf + (size_t)node * 64 + c8 * 8) = ob;
        } else {
            float4* op = (float4*)(out_f + (size_t)node * 64 + c8 * 8);
            op[0] = make_float4(y[0], y[1], y[2], y[3]);
            op[1] = make_float4(y[4], y[5], y[6], y[7]);
        }
    }
}

// ---------------------------------------------------------------------------
// Final Linear 64->32 (LN already applied by fused_attn<0,0>)
// ---------------------------------------------------------------------------
__global__ __launch_bounds__(256) void final_matvec(
    const float* __restrict__ y, const float* __restrict__ Wf,
    const float* __restrict__ bfv, float* __restrict__ out, int n)
{
    __shared__ float ys[8][64];
    int nb = blockIdx.x * 8;
    for (int i = threadIdx.x; i < 512; i += 256) {
        int r = i >> 6, c = i & 63;
        int gn = nb + r;
        ys[r][c] = (gn < n) ? y[(size_t)gn * 64 + c] : 0.f;
    }
    __syncthreads();
    int r = threadIdx.x >> 5, o = threadIdx.x & 31;
    int gn = nb + r;
    if (gn < n) {
        float a = bfv[o];
        #pragma unroll
        for (int c = 0; c < 64; ++c) a = fmaf(ys[r][c], Wf[c * 32 + o], a);
        out[(size_t)gn * 32 + o] = a;
    }
}

// ---------------------------------------------------------------------------
extern "C" void kernel_launch(void* const* d_in, const int* in_sizes, int n_in,
                              void* d_out, int out_size, void* d_ws, size_t ws_size,
                              hipStream_t stream)
{
    const float* x   = (const float*)d_in[0];
    const int*   ei  = (const int*)d_in[1];
    const float* Wq1 = (const float*)d_in[2];  const float* bq1 = (const float*)d_in[3];
    const float* Wk1 = (const float*)d_in[4];  const float* bk1 = (const float*)d_in[5];
    const float* Wv1 = (const float*)d_in[6];  const float* bv1 = (const float*)d_in[7];
    const float* Ws1 = (const float*)d_in[8];  const float* bs1 = (const float*)d_in[9];
    const float* Wq2 = (const float*)d_in[10]; const float* bq2 = (const float*)d_in[11];
    const float* Wk2 = (const float*)d_in[12]; const float* bk2 = (const float*)d_in[13];
    const float* Wv2 = (const float*)d_in[14]; const float* bv2 = (const float*)d_in[15];
    const float* Ws2 = (const float*)d_in[16]; const float* bs2 = (const float*)d_in[17];
    const float* lng = (const float*)d_in[18]; const float* lnb = (const float*)d_in[19];
    const float* Wf  = (const float*)d_in[20]; const float* bf  = (const float*)d_in[21];

    const int N = in_sizes[0] / 64;
    const int E = in_sizes[1] / 2;
    const int* src  = ei;
    const int* dstp = ei + E;

    char* p = (char*)d_ws;
    u16* qb   = (u16*)p; p += (size_t)N * 256 * 2;
    u16* kb   = (u16*)p; p += (size_t)N * 256 * 2;
    u16* vb   = (u16*)p; p += (size_t)N * 256 * 2;
    u16* xbf  = (u16*)p; p += (size_t)N * 64 * 2;   // conv1 output h (bf16)
    u16* wt1  = (u16*)p; p += 832 * 64 * 2;
    u16* wt2  = (u16*)p; p += 832 * 64 * 2;
    float* ba1  = (float*)p; p += 832 * 4;
    float* ba2  = (float*)p; p += 832 * 4;
    float* skip = (float*)p; p += (size_t)N * 64 * 4;
    float* y2   = (float*)p; p += (size_t)N * 64 * 4;
    int* deg    = (int*)p; p += (size_t)N * 4;
    int* off    = (int*)p; p += ((size_t)N + 1) * 4;
    int* cursor = (int*)p; p += (size_t)N * 4;
    int* csr    = (int*)p; p += (size_t)E * 4;
    int* bsum   = (int*)p; p += 1024;
    int* bpre   = (int*)p; p += 1024;

    const int cvw_blocks  = (832 * 64 + 255) / 256;
    const int e_blocks    = (E + 255) / 256;
    const int n_blocks    = (N + 255) / 256;
    const int gemm_blocks = (N + 15) / 16;
    const int attn_blocks = (N + 3) / 4;            // 1 node/wave, 4 waves/blk
    const int fin_blocks  = (N + 7) / 8;

    // ---- prep: conversions + CSR ----
    convert_w<<<cvw_blocks, 256, 0, stream>>>(Wq1, Wk1, Wv1, Ws1, bq1, bk1, bv1, bs1, wt1, ba1);
    convert_w<<<cvw_blocks, 256, 0, stream>>>(Wq2, Wk2, Wv2, Ws2, bq2, bk2, bv2, bs2, wt2, ba2);
    hipMemsetAsync(deg, 0, (size_t)N * 4, stream);
    hist_kernel<<<e_blocks, 256, 0, stream>>>(dstp, deg, E);
    scanA<<<n_blocks, 256, 0, stream>>>(deg, bsum, N);
    scanB<<<1, 256, 0, stream>>>(bsum, bpre, n_blocks);
    scanC<<<n_blocks, 256, 0, stream>>>(deg, bpre, off, cursor, N, E);
    fill_kernel<<<e_blocks, 256, 0, stream>>>(src, dstp, cursor, csr, E);

    // ---- conv1 (reads fp32 x directly) ----
    gemm_qkvs<1><<<gemm_blocks, 256, 0, stream>>>(x, wt1, ba1, qb, kb, vb, skip, N);
    fused_attn<1, 1><<<attn_blocks, 256, 0, stream>>>(qb, kb, vb, skip, off, csr,
                                                      lng, lnb, xbf, nullptr, N);
    // ---- conv2 ----
    gemm_qkvs<0><<<gemm_blocks, 256, 0, stream>>>(xbf, wt2, ba2, qb, kb, vb, skip, N);
    fused_attn<0, 0><<<attn_blocks, 256, 0, stream>>>(qb, kb, vb, skip, off, csr,
                                                      lng, lnb, nullptr, y2, N);
    // ---- final linear ----
    final_matvec<<<fin_blocks, 256, 0, stream>>>(y2, Wf, bf, (float*)d_out, N);
}